// Round 10
// baseline (1802.258 us; speedup 1.0000x reference)
//
#include <hip/hip_runtime.h>

typedef short bf16x8 __attribute__((ext_vector_type(8)));
typedef float floatx4 __attribute__((ext_vector_type(4)));
typedef float floatx2 __attribute__((ext_vector_type(2)));

typedef const __attribute__((address_space(1))) void* gas_ptr;
typedef __attribute__((address_space(3))) void* las_ptr;

#define EPB  4096   // edges per hist/scatter chunk
#define MAXB 6144   // bucket capacity (mean 4096, 32 sigma headroom)
#define NBLK 1024   // 4 blocks/CU x 256 CUs -- co-resident by construction

__device__ __forceinline__ unsigned short f2bf(float f) {
    unsigned int u = __float_as_uint(f);
    unsigned int r = u + 0x7fffu + ((u >> 16) & 1u);   // RNE
    return (unsigned short)(r >> 16);
}

__device__ __forceinline__ void stage16(const void* g, void* lbase, int lane) {
#if __has_builtin(__builtin_amdgcn_global_load_lds)
    __builtin_amdgcn_global_load_lds((gas_ptr)g, (las_ptr)lbase, 16, 0, 0);
#else
    *(float4*)((char*)lbase + lane * 16) = *(const float4*)g;
#endif
}

// Grid barrier: monotonic counter, all NBLK blocks co-resident (see launch cfg).
// __threadfence() = agent-scope fence -> L2 writeback/inv for cross-XCD visibility.
__device__ __forceinline__ void gbar(int* bar, int target) {
    __syncthreads();
    __threadfence();
    if (threadIdx.x == 0) {
        __hip_atomic_fetch_add(bar, 1, __ATOMIC_ACQ_REL, __HIP_MEMORY_SCOPE_AGENT);
        while (__hip_atomic_load(bar, __ATOMIC_ACQUIRE, __HIP_MEMORY_SCOPE_AGENT) < target)
            __builtin_amdgcn_s_sleep(2);
    }
    __syncthreads();
    __threadfence();
}

__global__ __launch_bounds__(256, 4) void mega(
    const float* __restrict__ h, const float* __restrict__ norm,
    const int* __restrict__ src, const int* __restrict__ dst,
    const int* __restrict__ rel, const float* __restrict__ basis,
    const float* __restrict__ coeff, const float* __restrict__ loopw,
    unsigned short* __restrict__ hbf, unsigned short* __restrict__ WT2,
    int* __restrict__ gh, int* __restrict__ binTot, int* __restrict__ sgh,
    unsigned int* __restrict__ tmp, unsigned int* __restrict__ sedge,
    int* __restrict__ rowptr, unsigned short* __restrict__ A2,
    float* __restrict__ out, int* __restrict__ bar,
    int N, int E, int R, int nB, int nblkH, int nb_conv)
{
    __shared__ alignas(16) unsigned char smem[32768];
    const int bid = blockIdx.x;
    const int t = threadIdx.x;

    // ================= P0: conv h->bf16 | coarse hist | weight transpose ======
    const int njobs0 = nb_conv + nblkH + 128;
    for (int j = bid; j < njobs0; j += NBLK) {
        if (j < nb_conv) {
            int idx = j * 256 + t;
            if (idx < N * 64) {
                float2 v = *(const float2*)(h + (size_t)idx * 2);
                unsigned int pack = (unsigned int)f2bf(v.x) | ((unsigned int)f2bf(v.y) << 16);
                *(unsigned int*)(hbf + (size_t)idx * 2) = pack;
            }
        } else if (j < nb_conv + nblkH) {
            int* lh = (int*)smem;
            const int blk = j - nb_conv;
            __syncthreads();
            lh[t] = 0;
            __syncthreads();
            const int cbase = blk * EPB;
#pragma unroll
            for (int jj = 0; jj < EPB / 256; ++jj) {
                int e = cbase + jj * 256 + t;
                if (e < E) atomicAdd(&lh[dst[e] >> 8], 1);
            }
            __syncthreads();
            if (t < nB) {
                gh[(size_t)t * nblkH + blk] = lh[t];
                atomicAdd(&binTot[t], lh[t]);          // no-return, cheap
            }
            __syncthreads();
        } else {
            int c = j - nb_conv - nblkH;               // 0..127
            for (int k = t; k < 640; k += 256) {
                float v;
                if (k < 512) v = basis[(size_t)k * 128 + c];
                else         v = loopw[(size_t)(k - 512) * 128 + c];
                WT2[(size_t)c * 640 + k] = f2bf(v);
            }
        }
    }
    gbar(bar, NBLK * 1);

    // ================= P1: per-bin scan -> sgh ================================
    for (int j = bid; j < nB; j += NBLK) {
        int* s1 = (int*)smem;          // bin-offset reduce
        int* s2 = s1 + 256;            // row scan
        __syncthreads();
        s1[t] = (t < j) ? binTot[t] : 0;
        s2[t] = (t < nblkH) ? gh[(size_t)j * nblkH + t] : 0;
        __syncthreads();
        for (int o = 128; o > 0; o >>= 1) {
            if (t < o) s1[t] += s1[t + o];
            __syncthreads();
        }
        int v = s2[t];
        for (int o = 1; o < 256; o <<= 1) {
            int x = (t >= o) ? s2[t - o] : 0;
            __syncthreads();
            s2[t] += x;
            __syncthreads();
        }
        if (t < nblkH) sgh[(size_t)j * nblkH + t] = s2[t] - v + s1[0];
    }
    gbar(bar, NBLK * 2);

    // ================= P2: route edges to coarse buckets ======================
    for (int j = bid; j < nblkH; j += NBLK) {
        int* cur = (int*)smem;
        __syncthreads();
        if (t < nB) cur[t] = sgh[(size_t)t * nblkH + j];
        __syncthreads();
        const int cbase = j * EPB;
#pragma unroll
        for (int jj = 0; jj < EPB / 256; ++jj) {
            int e = cbase + jj * 256 + t;
            if (e < E) {
                int d = dst[e];
                int slot = atomicAdd(&cur[d >> 8], 1);
                tmp[slot] = (unsigned int)src[e] | ((unsigned int)rel[e] << 16)
                          | ((unsigned int)(d & 255) << 23);
            }
        }
        __syncthreads();
    }
    gbar(bar, NBLK * 3);

    // ================= P3: in-bucket sort by dst&255, emit rowptr + sedge =====
    for (int j = bid; j < nB; j += NBLK) {
        unsigned int* eb = (unsigned int*)smem;        // 24576 B
        int* hh  = (int*)(smem + 24576);
        int* ss  = hh + 256;
        int* cur = ss + 256;
        __syncthreads();
        const int brow = sgh[(size_t)j * nblkH];
        const int next = (j + 1 < nB) ? sgh[(size_t)(j + 1) * nblkH] : E;
        int n = next - brow;
        if (n > MAXB) n = MAXB;                        // statistically unreachable
        hh[t] = 0;
        __syncthreads();
        for (int i = t; i < n; i += 256) {
            unsigned int v = tmp[brow + i];
            eb[i] = v;
            atomicAdd(&hh[(v >> 23) & 255], 1);
        }
        __syncthreads();
        int v = hh[t];
        ss[t] = v;
        __syncthreads();
        for (int o = 1; o < 256; o <<= 1) {
            int x = (t >= o) ? ss[t - o] : 0;
            __syncthreads();
            ss[t] += x;
            __syncthreads();
        }
        const int excl = ss[t] - v;
        const int idx = j * 256 + t;
        if (idx <= N) rowptr[idx] = brow + excl;       // covers rowptr[N]=E
        cur[t] = excl;
        __syncthreads();
        for (int i = t; i < n; i += 256) {
            unsigned int e = eb[i];
            int slot = atomicAdd(&cur[(e >> 23) & 255], 1);
            sedge[brow + slot] = ((e & 0xFFFFu) << 8) | (((e >> 16) & 0x7Fu) << 25);
        }
        __syncthreads();
    }
    gbar(bar, NBLK * 4);

    // ================= P4: aggregate h_bf[src] per dst -> A2 ==================
    {
        float* scoef = (float*)smem;                   // R*4 <= 512 floats
        __syncthreads();
        for (int i = t; i < R * 4; i += 256) scoef[i] = coeff[i];
        __syncthreads();

        const int wave = t >> 6;
        const int lane = t & 63;
        const char* hbase = (const char*)hbf + lane * 4;
        const int njobs = (N + 3) / 4;

        for (int j = bid; j < njobs; j += NBLK) {
            const int d = j * 4 + wave;
            if (d >= N) continue;
            int i = rowptr[d];
            const int end = rowptr[d + 1];

            floatx2 a0 = {0.f, 0.f}, a1 = {0.f, 0.f}, a2 = {0.f, 0.f}, a3 = {0.f, 0.f};

#define EDGE_LOAD(v, u) \
    unsigned int u = *(const unsigned int*)(hbase + ((v) & 0x00FFFF00u));
#define EDGE_MATH(v, u) { \
    const float4 c = *(const float4*)((const char*)scoef + (((v) >> 25) << 4)); \
    floatx2 hp; \
    hp[0] = __uint_as_float((u) << 16); \
    hp[1] = __uint_as_float((u) & 0xFFFF0000u); \
    a0 = __builtin_elementwise_fma((floatx2){c.x, c.x}, hp, a0); \
    a1 = __builtin_elementwise_fma((floatx2){c.y, c.y}, hp, a1); \
    a2 = __builtin_elementwise_fma((floatx2){c.z, c.z}, hp, a2); \
    a3 = __builtin_elementwise_fma((floatx2){c.w, c.w}, hp, a3); }

            while (i < end && (i & 3)) {
                unsigned int v = sedge[i];
                EDGE_LOAD(v, u)
                EDGE_MATH(v, u)
                ++i;
            }
            for (; i + 8 <= end; i += 8) {
                uint4 e0 = *(const uint4*)(sedge + i);
                uint4 e1 = *(const uint4*)(sedge + i + 4);
                EDGE_LOAD(e0.x, u0) EDGE_LOAD(e0.y, u1) EDGE_LOAD(e0.z, u2) EDGE_LOAD(e0.w, u3)
                EDGE_LOAD(e1.x, u4) EDGE_LOAD(e1.y, u5) EDGE_LOAD(e1.z, u6) EDGE_LOAD(e1.w, u7)
                EDGE_MATH(e0.x, u0) EDGE_MATH(e0.y, u1) EDGE_MATH(e0.z, u2) EDGE_MATH(e0.w, u3)
                EDGE_MATH(e1.x, u4) EDGE_MATH(e1.y, u5) EDGE_MATH(e1.z, u6) EDGE_MATH(e1.w, u7)
            }
            for (; i + 4 <= end; i += 4) {
                uint4 e0 = *(const uint4*)(sedge + i);
                EDGE_LOAD(e0.x, u0) EDGE_LOAD(e0.y, u1) EDGE_LOAD(e0.z, u2) EDGE_LOAD(e0.w, u3)
                EDGE_MATH(e0.x, u0) EDGE_MATH(e0.y, u1) EDGE_MATH(e0.z, u2) EDGE_MATH(e0.w, u3)
            }
            for (; i < end; ++i) {
                unsigned int v = sedge[i];
                EDGE_LOAD(v, u)
                EDGE_MATH(v, u)
            }
#undef EDGE_LOAD
#undef EDGE_MATH

            const float nm = norm[d];
            unsigned short* row = A2 + (size_t)d * 512 + lane * 2;
            *(unsigned int*)(row)       = (unsigned int)f2bf(a0[0] * nm) | ((unsigned int)f2bf(a0[1] * nm) << 16);
            *(unsigned int*)(row + 128) = (unsigned int)f2bf(a1[0] * nm) | ((unsigned int)f2bf(a1[1] * nm) << 16);
            *(unsigned int*)(row + 256) = (unsigned int)f2bf(a2[0] * nm) | ((unsigned int)f2bf(a2[1] * nm) << 16);
            *(unsigned int*)(row + 384) = (unsigned int)f2bf(a3[0] * nm) | ((unsigned int)f2bf(a3[1] * nm) << 16);
        }
    }
    gbar(bar, NBLK * 5);

    // ================= P5: out = relu([A2|hbf] @ WT2^T), LDS-tiled MFMA ======
    {
        char* sA = (char*)smem;            // 16384: [kc 0..7][row 0..127] x 16B
        char* sB = (char*)smem + 16384;    // 16384: [kc 0..7][col 0..127] x 16B
        const int w = t >> 6;
        const int lane = t & 63;
        const int quad = lane >> 4;
        const int low  = lane & 15;
        const int wr = w >> 1, wc = w & 1;
        const int njobs = (N + 127) / 128;

        for (int j = bid; j < njobs; j += NBLK) {
            const int m0 = j * 128;
            floatx4 acc[4][4];
#pragma unroll
            for (int mt = 0; mt < 4; ++mt)
#pragma unroll
                for (int nt = 0; nt < 4; ++nt) acc[mt][nt] = (floatx4){0.f, 0.f, 0.f, 0.f};

            __syncthreads();
            for (int it = 0; it < 10; ++it) {
                const int k0 = it * 64;
#pragma unroll
                for (int i = 0; i < 4; ++i) {
                    const int slot = i * 256 + t;
                    const int kc  = slot >> 7;
                    const int idx = slot & 127;
                    int grow = m0 + idx;
                    if (grow >= N) grow = N - 1;
                    const unsigned short* gA = (k0 < 512)
                        ? A2  + (size_t)grow * 512 + k0 + kc * 8
                        : hbf + (size_t)grow * 128 + (k0 - 512) + kc * 8;
                    const unsigned short* gB = WT2 + (size_t)idx * 640 + k0 + kc * 8;
                    stage16(gA, sA + (size_t)(i * 256 + w * 64) * 16, lane);
                    stage16(gB, sB + (size_t)(i * 256 + w * 64) * 16, lane);
                }
                __syncthreads();
#pragma unroll
                for (int ks = 0; ks < 2; ++ks) {
                    bf16x8 af[4], bfr[4];
#pragma unroll
                    for (int mt = 0; mt < 4; ++mt)
                        af[mt] = *(const bf16x8*)(sA + (size_t)(((ks * 4 + quad) << 7) + wr * 64 + mt * 16 + low) * 16);
#pragma unroll
                    for (int nt = 0; nt < 4; ++nt)
                        bfr[nt] = *(const bf16x8*)(sB + (size_t)(((ks * 4 + quad) << 7) + wc * 64 + nt * 16 + low) * 16);
#pragma unroll
                    for (int mt = 0; mt < 4; ++mt)
#pragma unroll
                        for (int nt = 0; nt < 4; ++nt)
                            acc[mt][nt] = __builtin_amdgcn_mfma_f32_16x16x32_bf16(af[mt], bfr[nt], acc[mt][nt], 0, 0, 0);
                }
                __syncthreads();
            }
#pragma unroll
            for (int mt = 0; mt < 4; ++mt) {
#pragma unroll
                for (int nt = 0; nt < 4; ++nt) {
                    const int c = wc * 64 + nt * 16 + low;
#pragma unroll
                    for (int r = 0; r < 4; ++r) {
                        int rr = m0 + wr * 64 + mt * 16 + quad * 4 + r;
                        if (rr < N) out[(size_t)rr * 128 + c] = fmaxf(acc[mt][nt][r], 0.f);
                    }
                }
            }
        }
    }
}

extern "C" void kernel_launch(void* const* d_in, const int* in_sizes, int n_in,
                              void* d_out, int out_size, void* d_ws, size_t ws_size,
                              hipStream_t stream)
{
    const float* h     = (const float*)d_in[0];
    const float* norm  = (const float*)d_in[1];
    const int*   src   = (const int*)d_in[2];
    const int*   dst   = (const int*)d_in[3];
    const int*   rel   = (const int*)d_in[4];
    const float* basis = (const float*)d_in[5];
    const float* coeff = (const float*)d_in[6];
    const float* loopw = (const float*)d_in[7];
    float* out = (float*)d_out;

    const int N = in_sizes[1];       // 50000
    const int E = in_sizes[2];       // 800000
    const int R = in_sizes[6] / 4;   // 100

    const int nB      = (N + 255) >> 8;          // 196 coarse buckets
    const int nblkH   = (E + EPB - 1) / EPB;     // 196 edge chunks
    const int M       = nB * nblkH;
    const int nb_conv = (N * 64 + 255) / 256;    // 12500

    char* ws = (char*)d_ws;
    size_t off = 0;
    auto walloc = [&](size_t bytes) -> char* {
        char* p = ws + off;
        off = (off + bytes + 255) & ~(size_t)255;
        return p;
    };
    unsigned short* A2     = (unsigned short*)walloc((size_t)N * 512 * 2);  // 51.2 MB
    unsigned short* hbf    = (unsigned short*)walloc((size_t)N * 128 * 2);  // 12.8 MB
    unsigned short* WT2    = (unsigned short*)walloc(128 * 640 * 2);
    int*            gh     = (int*)walloc((size_t)M * 4);
    int*            sgh    = (int*)walloc((size_t)M * 4);
    unsigned int*   tmp    = (unsigned int*)walloc((size_t)E * 4);
    unsigned int*   sedge  = (unsigned int*)walloc((size_t)E * 4);
    int*            rowptr = (int*)walloc((size_t)(N + 1) * 4);
    char*           ctrl   = walloc(2048);       // bar @0, binTot @256
    int*            bar    = (int*)ctrl;
    int*            binTot = (int*)(ctrl + 256);

    hipMemsetAsync(ctrl, 0, 2048, stream);
    mega<<<NBLK, 256, 0, stream>>>(
        h, norm, src, dst, rel, basis, coeff, loopw,
        hbf, WT2, gh, binTot, sgh, tmp, sedge, rowptr, A2, out, bar,
        N, E, R, nB, nblkH, nb_conv);
}

// Round 11
// 280.662 us; speedup vs baseline: 6.4215x; 6.4215x over previous
//
#include <hip/hip_runtime.h>

typedef short bf16x8 __attribute__((ext_vector_type(8)));
typedef float floatx4 __attribute__((ext_vector_type(4)));
typedef float floatx2 __attribute__((ext_vector_type(2)));

typedef const __attribute__((address_space(1))) void* gas_ptr;
typedef __attribute__((address_space(3))) void* las_ptr;

#define EPB  4096   // edges per hist/scatter chunk
#define MAXB 6144   // bucket capacity (mean 4096, 32 sigma headroom)

__device__ __forceinline__ unsigned short f2bf(float f) {
    unsigned int u = __float_as_uint(f);
    unsigned int r = u + 0x7fffu + ((u >> 16) & 1u);   // RNE
    return (unsigned short)(r >> 16);
}

__device__ __forceinline__ void stage16(const void* g, void* lbase, int lane) {
#if __has_builtin(__builtin_amdgcn_global_load_lds)
    __builtin_amdgcn_global_load_lds((gas_ptr)g, (las_ptr)lbase, 16, 0, 0);
#else
    *(float4*)((char*)lbase + lane * 16) = *(const float4*)g;
#endif
}

// Fused prep: blocks [0,nb_conv) convert h->bf16; next nblkH blocks build the
// per-chunk coarse-bucket (dst>>8) LDS histogram -> gh[bin][blk]; last 128
// blocks transpose weights. No global atomics anywhere.
__global__ __launch_bounds__(256) void prep_all(
    const float* __restrict__ h, unsigned short* __restrict__ hbf, int nconv,
    const int* __restrict__ dst, int* __restrict__ gh, int E, int nB, int nblkH,
    const float* __restrict__ basis, const float* __restrict__ loopw,
    unsigned short* __restrict__ WT2, int nb_conv)
{
    __shared__ int lh[256];
    const int b = blockIdx.x;
    const int t = threadIdx.x;
    if (b < nb_conv) {
        int idx = b * 256 + t;
        if (idx < nconv) {
            float2 v = *(const float2*)(h + (size_t)idx * 2);
            unsigned int pack = (unsigned int)f2bf(v.x) | ((unsigned int)f2bf(v.y) << 16);
            *(unsigned int*)(hbf + (size_t)idx * 2) = pack;
        }
    } else if (b < nb_conv + nblkH) {
        const int blk = b - nb_conv;
        lh[t] = 0;
        __syncthreads();
        const int cbase = blk * EPB;
#pragma unroll
        for (int j = 0; j < EPB / 256; ++j) {
            int e = cbase + j * 256 + t;
            if (e < E) atomicAdd(&lh[dst[e] >> 8], 1);
        }
        __syncthreads();
        if (t < nB) gh[(size_t)t * nblkH + blk] = lh[t];
    } else {
        int c = b - nb_conv - nblkH;            // 0..127
        for (int k = t; k < 640; k += 256) {
            float v;
            if (k < 512) v = basis[(size_t)k * 128 + c];
            else         v = loopw[(size_t)(k - 512) * 128 + c];
            WT2[(size_t)c * 640 + k] = f2bf(v);
        }
    }
}

// Route edges into coarse buckets. Each block derives its own cursors in-block:
// thread t (=bin t) sums its gh row -> total + prefix over chunks < blockIdx;
// LDS scan of totals gives global bucket starts. Block 0 publishes binStart.
// tmp packing: src(16) | rel<<16(7) | (dst&255)<<23(8).
__global__ __launch_bounds__(256) void scatter_bkt(
    const int* __restrict__ dst, const int* __restrict__ src,
    const int* __restrict__ rel, const int* __restrict__ gh,
    int* __restrict__ binStart, unsigned int* __restrict__ tmp,
    int E, int nB, int nblkH)
{
    __shared__ int ss[256];
    __shared__ int cur[256];
    const int j = blockIdx.x;
    const int t = threadIdx.x;

    int pre = 0, tot = 0;
    if (t < nB) {
        const int* row = gh + (size_t)t * nblkH;
#pragma unroll 8
        for (int c = 0; c < nblkH; ++c) {
            int v = row[c];
            tot += v;
            if (c < j) pre += v;
        }
    }
    int v = (t < nB) ? tot : 0;
    ss[t] = v;
    __syncthreads();
    for (int o = 1; o < 256; o <<= 1) {         // inclusive scan of bin totals
        int x = (t >= o) ? ss[t - o] : 0;
        __syncthreads();
        ss[t] += x;
        __syncthreads();
    }
    const int gstart = ss[t] - v;               // exclusive: global bucket start
    cur[t] = gstart + pre;
    if (j == 0) {
        if (t < nB) binStart[t] = gstart;
        if (t == 0) binStart[nB] = E;
    }
    __syncthreads();

    const int cbase = j * EPB;
#pragma unroll
    for (int jj = 0; jj < EPB / 256; ++jj) {
        int e = cbase + jj * 256 + t;
        if (e < E) {
            int d = dst[e];
            int slot = atomicAdd(&cur[d >> 8], 1);
            tmp[slot] = (unsigned int)src[e] | ((unsigned int)rel[e] << 16)
                      | ((unsigned int)(d & 255) << 23);
        }
    }
}

// One block per bucket: finish sort by dst&255 in LDS, emit rowptr + sedge
// (packed src<<8 | rel<<25).
__global__ __launch_bounds__(256) void bucket_sort(
    const unsigned int* __restrict__ tmp, const int* __restrict__ binStart,
    unsigned int* __restrict__ sedge, int* __restrict__ rowptr,
    int E, int N, int nB)
{
    __shared__ unsigned int eb[MAXB];
    __shared__ int hh[256], ss[256], cur[256];
    const int b = blockIdx.x;
    const int t = threadIdx.x;
    const int brow = binStart[b];
    const int next = binStart[b + 1];
    int n = next - brow;
    if (n > MAXB) n = MAXB;                     // statistically unreachable
    hh[t] = 0;
    __syncthreads();
    for (int i = t; i < n; i += 256) {
        unsigned int v = tmp[brow + i];
        eb[i] = v;
        atomicAdd(&hh[(v >> 23) & 255], 1);
    }
    __syncthreads();
    int v = hh[t];
    ss[t] = v;
    __syncthreads();
    for (int o = 1; o < 256; o <<= 1) {
        int x = (t >= o) ? ss[t - o] : 0;
        __syncthreads();
        ss[t] += x;
        __syncthreads();
    }
    const int excl = ss[t] - v;
    const int idx = b * 256 + t;
    if (idx <= N) rowptr[idx] = brow + excl;    // covers rowptr[N]=E
    cur[t] = excl;
    __syncthreads();
    for (int i = t; i < n; i += 256) {
        unsigned int e = eb[i];
        int slot = atomicAdd(&cur[(e >> 23) & 255], 1);
        sedge[brow + slot] = ((e & 0xFFFFu) << 8) | (((e >> 16) & 0x7Fu) << 25);
    }
}

// Fused aggregate + GEMM. Block owns 128 dst rows:
//   Phase A: 4 waves x 32 contiguous dsts — gather h_bf[src], accumulate 4
//            basis float2 pairs/lane, scale by norm, write bf16 A2 rows.
//   Phase B: out[m0..m0+127] = relu([A2|hbf] @ WT2^T), LDS-tiled MFMA (A2 L2-hot).
__global__ __launch_bounds__(256) void agg_gemm(
    const unsigned short* __restrict__ hbf,
    const int* __restrict__ rowptr,
    const unsigned int* __restrict__ sedge,
    const float* __restrict__ coeff,
    const float* __restrict__ norm,
    unsigned short* __restrict__ A2,
    const unsigned short* __restrict__ WT2,
    float* __restrict__ out, int N, int R)
{
    __shared__ alignas(16) unsigned char smem[32768];
    const int t = threadIdx.x;
    const int m0 = blockIdx.x * 128;

    // ---------------- Phase A: aggregation ----------------
    {
        float* scoef = (float*)smem;            // R*4 <= 512 floats
        for (int i = t; i < R * 4; i += 256) scoef[i] = coeff[i];
        __syncthreads();

        const int wave = t >> 6;
        const int lane = t & 63;
        const char* hbase = (const char*)hbf + lane * 4;

        for (int k = 0; k < 32; ++k) {
            const int d = m0 + wave * 32 + k;   // wave-contiguous dst runs
            if (d >= N) break;
            int i = rowptr[d];
            const int end = rowptr[d + 1];

            floatx2 a0 = {0.f, 0.f}, a1 = {0.f, 0.f}, a2 = {0.f, 0.f}, a3 = {0.f, 0.f};

#define EDGE_LOAD(v, u) \
    unsigned int u = *(const unsigned int*)(hbase + ((v) & 0x00FFFF00u));
#define EDGE_MATH(v, u) { \
    const float4 c = *(const float4*)((const char*)scoef + (((v) >> 25) << 4)); \
    floatx2 hp; \
    hp[0] = __uint_as_float((u) << 16); \
    hp[1] = __uint_as_float((u) & 0xFFFF0000u); \
    a0 = __builtin_elementwise_fma((floatx2){c.x, c.x}, hp, a0); \
    a1 = __builtin_elementwise_fma((floatx2){c.y, c.y}, hp, a1); \
    a2 = __builtin_elementwise_fma((floatx2){c.z, c.z}, hp, a2); \
    a3 = __builtin_elementwise_fma((floatx2){c.w, c.w}, hp, a3); }

            while (i < end && (i & 3)) {
                unsigned int v = sedge[i];
                EDGE_LOAD(v, u)
                EDGE_MATH(v, u)
                ++i;
            }
            for (; i + 8 <= end; i += 8) {
                uint4 e0 = *(const uint4*)(sedge + i);
                uint4 e1 = *(const uint4*)(sedge + i + 4);
                EDGE_LOAD(e0.x, u0) EDGE_LOAD(e0.y, u1) EDGE_LOAD(e0.z, u2) EDGE_LOAD(e0.w, u3)
                EDGE_LOAD(e1.x, u4) EDGE_LOAD(e1.y, u5) EDGE_LOAD(e1.z, u6) EDGE_LOAD(e1.w, u7)
                EDGE_MATH(e0.x, u0) EDGE_MATH(e0.y, u1) EDGE_MATH(e0.z, u2) EDGE_MATH(e0.w, u3)
                EDGE_MATH(e1.x, u4) EDGE_MATH(e1.y, u5) EDGE_MATH(e1.z, u6) EDGE_MATH(e1.w, u7)
            }
            for (; i + 4 <= end; i += 4) {
                uint4 e0 = *(const uint4*)(sedge + i);
                EDGE_LOAD(e0.x, u0) EDGE_LOAD(e0.y, u1) EDGE_LOAD(e0.z, u2) EDGE_LOAD(e0.w, u3)
                EDGE_MATH(e0.x, u0) EDGE_MATH(e0.y, u1) EDGE_MATH(e0.z, u2) EDGE_MATH(e0.w, u3)
            }
            for (; i < end; ++i) {
                unsigned int v = sedge[i];
                EDGE_LOAD(v, u)
                EDGE_MATH(v, u)
            }
#undef EDGE_LOAD
#undef EDGE_MATH

            const float nm = norm[d];
            unsigned short* row = A2 + (size_t)d * 512 + lane * 2;
            *(unsigned int*)(row)       = (unsigned int)f2bf(a0[0] * nm) | ((unsigned int)f2bf(a0[1] * nm) << 16);
            *(unsigned int*)(row + 128) = (unsigned int)f2bf(a1[0] * nm) | ((unsigned int)f2bf(a1[1] * nm) << 16);
            *(unsigned int*)(row + 256) = (unsigned int)f2bf(a2[0] * nm) | ((unsigned int)f2bf(a2[1] * nm) << 16);
            *(unsigned int*)(row + 384) = (unsigned int)f2bf(a3[0] * nm) | ((unsigned int)f2bf(a3[1] * nm) << 16);
        }
    }
    __syncthreads();   // drains vmcnt: this block's A2 rows visible to phase B

    // ---------------- Phase B: 128-row GEMM ----------------
    {
        char* sA = (char*)smem;            // [kc 0..7][row 0..127] x 16B
        char* sB = (char*)smem + 16384;    // [kc 0..7][col 0..127] x 16B
        const int w = t >> 6;
        const int lane = t & 63;
        const int quad = lane >> 4;
        const int low  = lane & 15;
        const int wr = w >> 1, wc = w & 1;

        floatx4 acc[4][4];
#pragma unroll
        for (int mt = 0; mt < 4; ++mt)
#pragma unroll
            for (int nt = 0; nt < 4; ++nt) acc[mt][nt] = (floatx4){0.f, 0.f, 0.f, 0.f};

        for (int it = 0; it < 10; ++it) {
            const int k0 = it * 64;
#pragma unroll
            for (int i = 0; i < 4; ++i) {
                const int slot = i * 256 + t;
                const int kc  = slot >> 7;
                const int idx = slot & 127;
                int grow = m0 + idx;
                if (grow >= N) grow = N - 1;
                const unsigned short* gA = (k0 < 512)
                    ? A2  + (size_t)grow * 512 + k0 + kc * 8
                    : hbf + (size_t)grow * 128 + (k0 - 512) + kc * 8;
                const unsigned short* gB = WT2 + (size_t)idx * 640 + k0 + kc * 8;
                stage16(gA, sA + (size_t)(i * 256 + w * 64) * 16, lane);
                stage16(gB, sB + (size_t)(i * 256 + w * 64) * 16, lane);
            }
            __syncthreads();
#pragma unroll
            for (int ks = 0; ks < 2; ++ks) {
                bf16x8 af[4], bfr[4];
#pragma unroll
                for (int mt = 0; mt < 4; ++mt)
                    af[mt] = *(const bf16x8*)(sA + (size_t)(((ks * 4 + quad) << 7) + wr * 64 + mt * 16 + low) * 16);
#pragma unroll
                for (int nt = 0; nt < 4; ++nt)
                    bfr[nt] = *(const bf16x8*)(sB + (size_t)(((ks * 4 + quad) << 7) + wc * 64 + nt * 16 + low) * 16);
#pragma unroll
                for (int mt = 0; mt < 4; ++mt)
#pragma unroll
                    for (int nt = 0; nt < 4; ++nt)
                        acc[mt][nt] = __builtin_amdgcn_mfma_f32_16x16x32_bf16(af[mt], bfr[nt], acc[mt][nt], 0, 0, 0);
            }
            __syncthreads();
        }

        // C/D: col=lane&15, row=(lane>>4)*4+reg
#pragma unroll
        for (int mt = 0; mt < 4; ++mt) {
#pragma unroll
            for (int nt = 0; nt < 4; ++nt) {
                const int c = wc * 64 + nt * 16 + low;
#pragma unroll
                for (int r = 0; r < 4; ++r) {
                    int rr = m0 + wr * 64 + mt * 16 + quad * 4 + r;
                    if (rr < N) out[(size_t)rr * 128 + c] = fmaxf(acc[mt][nt][r], 0.f);
                }
            }
        }
    }
}

extern "C" void kernel_launch(void* const* d_in, const int* in_sizes, int n_in,
                              void* d_out, int out_size, void* d_ws, size_t ws_size,
                              hipStream_t stream)
{
    const float* h     = (const float*)d_in[0];
    const float* norm  = (const float*)d_in[1];
    const int*   src   = (const int*)d_in[2];
    const int*   dst   = (const int*)d_in[3];
    const int*   rel   = (const int*)d_in[4];
    const float* basis = (const float*)d_in[5];
    const float* coeff = (const float*)d_in[6];
    const float* loopw = (const float*)d_in[7];
    float* out = (float*)d_out;

    const int N = in_sizes[1];       // 50000
    const int E = in_sizes[2];       // 800000
    const int R = in_sizes[6] / 4;   // 100

    const int nB      = (N + 255) >> 8;          // 196 coarse buckets
    const int nblkH   = (E + EPB - 1) / EPB;     // 196 edge chunks
    const int M       = nB * nblkH;
    const int nb_conv = (N * 64 + 255) / 256;    // 12500

    char* ws = (char*)d_ws;
    size_t off = 0;
    auto walloc = [&](size_t bytes) -> char* {
        char* p = ws + off;
        off = (off + bytes + 255) & ~(size_t)255;
        return p;
    };
    unsigned short* A2       = (unsigned short*)walloc((size_t)N * 512 * 2);  // 51.2 MB
    unsigned short* hbf      = (unsigned short*)walloc((size_t)N * 128 * 2);  // 12.8 MB
    unsigned short* WT2      = (unsigned short*)walloc(128 * 640 * 2);
    int*            gh       = (int*)walloc((size_t)M * 4);
    int*            binStart = (int*)walloc((size_t)(nB + 1) * 4);
    unsigned int*   tmp      = (unsigned int*)walloc((size_t)E * 4);
    unsigned int*   sedge    = (unsigned int*)walloc((size_t)E * 4);
    int*            rowptr   = (int*)walloc((size_t)(N + 1) * 4);

    prep_all<<<nb_conv + nblkH + 128, 256, 0, stream>>>(
        h, hbf, nb_conv * 256 < N * 64 ? N * 64 : N * 64, dst, gh, E, nB, nblkH,
        basis, loopw, WT2, nb_conv);
    scatter_bkt<<<nblkH, 256, 0, stream>>>(dst, src, rel, gh, binStart, tmp, E, nB, nblkH);
    bucket_sort<<<nB, 256, 0, stream>>>(tmp, binStart, sedge, rowptr, E, N, nB);
    agg_gemm<<<(N + 127) / 128, 256, 0, stream>>>(
        hbf, rowptr, sedge, coeff, norm, A2, WT2, out, N, R);
}

// Round 12
// 206.662 us; speedup vs baseline: 8.7208x; 1.3581x over previous
//
#include <hip/hip_runtime.h>

typedef short bf16x8 __attribute__((ext_vector_type(8)));
typedef float floatx4 __attribute__((ext_vector_type(4)));
typedef float floatx2 __attribute__((ext_vector_type(2)));

typedef const __attribute__((address_space(1))) void* gas_ptr;
typedef __attribute__((address_space(3))) void* las_ptr;

#define EPB  4096   // edges per hist/scatter chunk
#define MAXB 6144   // bucket capacity (mean 4096, 32 sigma headroom)

__device__ __forceinline__ unsigned short f2bf(float f) {
    unsigned int u = __float_as_uint(f);
    unsigned int r = u + 0x7fffu + ((u >> 16) & 1u);   // RNE
    return (unsigned short)(r >> 16);
}

__device__ __forceinline__ void stage16(const void* g, void* lbase, int lane) {
#if __has_builtin(__builtin_amdgcn_global_load_lds)
    __builtin_amdgcn_global_load_lds((gas_ptr)g, (las_ptr)lbase, 16, 0, 0);
#else
    *(float4*)((char*)lbase + lane * 16) = *(const float4*)g;
#endif
}

// Fused prep: blocks [0,nb_conv) convert h->bf16; next nblkH blocks build the
// per-chunk coarse-bucket (dst>>8) LDS histogram -> gh[bin][blk]; last 128
// blocks transpose weights. No global atomics.
__global__ __launch_bounds__(256) void prep_all(
    const float* __restrict__ h, unsigned short* __restrict__ hbf, int nconv,
    const int* __restrict__ dst, int* __restrict__ gh, int E, int nB, int nblkH,
    const float* __restrict__ basis, const float* __restrict__ loopw,
    unsigned short* __restrict__ WT2, int nb_conv)
{
    __shared__ int lh[256];
    const int b = blockIdx.x;
    const int t = threadIdx.x;
    if (b < nb_conv) {
        int idx = b * 256 + t;
        if (idx < nconv) {
            float2 v = *(const float2*)(h + (size_t)idx * 2);
            unsigned int pack = (unsigned int)f2bf(v.x) | ((unsigned int)f2bf(v.y) << 16);
            *(unsigned int*)(hbf + (size_t)idx * 2) = pack;
        }
    } else if (b < nb_conv + nblkH) {
        const int blk = b - nb_conv;
        lh[t] = 0;
        __syncthreads();
        const int cbase = blk * EPB;
#pragma unroll
        for (int j = 0; j < EPB / 256; ++j) {
            int e = cbase + j * 256 + t;
            if (e < E) atomicAdd(&lh[dst[e] >> 8], 1);
        }
        __syncthreads();
        if (t < nB) gh[(size_t)t * nblkH + blk] = lh[t];
    } else {
        int c = b - nb_conv - nblkH;            // 0..127
        for (int k = t; k < 640; k += 256) {
            float v;
            if (k < 512) v = basis[(size_t)k * 128 + c];
            else         v = loopw[(size_t)(k - 512) * 128 + c];
            WT2[(size_t)c * 640 + k] = f2bf(v);
        }
    }
}

// Route edges into coarse buckets. Each block derives its own cursors in-block
// (thread t = bin t: row-sum of gh -> total + prefix over chunks < blockIdx;
// LDS scan of totals -> global bucket starts). Block 0 publishes binStart.
// tmp packing: src(16) | rel<<16(7) | (dst&255)<<23(8).
__global__ __launch_bounds__(256) void scatter_bkt(
    const int* __restrict__ dst, const int* __restrict__ src,
    const int* __restrict__ rel, const int* __restrict__ gh,
    int* __restrict__ binStart, unsigned int* __restrict__ tmp,
    int E, int nB, int nblkH)
{
    __shared__ int ss[256];
    __shared__ int cur[256];
    const int j = blockIdx.x;
    const int t = threadIdx.x;

    int pre = 0, tot = 0;
    if (t < nB) {
        const int* row = gh + (size_t)t * nblkH;
#pragma unroll 8
        for (int c = 0; c < nblkH; ++c) {
            int v = row[c];
            tot += v;
            if (c < j) pre += v;
        }
    }
    int v = (t < nB) ? tot : 0;
    ss[t] = v;
    __syncthreads();
    for (int o = 1; o < 256; o <<= 1) {         // inclusive scan of bin totals
        int x = (t >= o) ? ss[t - o] : 0;
        __syncthreads();
        ss[t] += x;
        __syncthreads();
    }
    const int gstart = ss[t] - v;               // exclusive global bucket start
    cur[t] = gstart + pre;
    if (j == 0) {
        if (t < nB) binStart[t] = gstart;
        if (t == 0) binStart[nB] = E;
    }
    __syncthreads();

    const int cbase = j * EPB;
#pragma unroll
    for (int jj = 0; jj < EPB / 256; ++jj) {
        int e = cbase + jj * 256 + t;
        if (e < E) {
            int d = dst[e];
            int slot = atomicAdd(&cur[d >> 8], 1);
            tmp[slot] = (unsigned int)src[e] | ((unsigned int)rel[e] << 16)
                      | ((unsigned int)(d & 255) << 23);
        }
    }
}

// One block per bucket: finish sort by dst&255 in LDS, emit rowptr + sedge
// (packed src<<8 | rel<<25).
__global__ __launch_bounds__(256) void bucket_sort(
    const unsigned int* __restrict__ tmp, const int* __restrict__ binStart,
    unsigned int* __restrict__ sedge, int* __restrict__ rowptr,
    int E, int N, int nB)
{
    __shared__ unsigned int eb[MAXB];
    __shared__ int hh[256], ss[256], cur[256];
    const int b = blockIdx.x;
    const int t = threadIdx.x;
    const int brow = binStart[b];
    const int next = binStart[b + 1];
    int n = next - brow;
    if (n > MAXB) n = MAXB;                     // statistically unreachable
    hh[t] = 0;
    __syncthreads();
    for (int i = t; i < n; i += 256) {
        unsigned int v = tmp[brow + i];
        eb[i] = v;
        atomicAdd(&hh[(v >> 23) & 255], 1);
    }
    __syncthreads();
    int v = hh[t];
    ss[t] = v;
    __syncthreads();
    for (int o = 1; o < 256; o <<= 1) {
        int x = (t >= o) ? ss[t - o] : 0;
        __syncthreads();
        ss[t] += x;
        __syncthreads();
    }
    const int excl = ss[t] - v;
    const int idx = b * 256 + t;
    if (idx <= N) rowptr[idx] = brow + excl;    // covers rowptr[N]=E
    cur[t] = excl;
    __syncthreads();
    for (int i = t; i < n; i += 256) {
        unsigned int e = eb[i];
        int slot = atomicAdd(&cur[(e >> 23) & 255], 1);
        sedge[brow + slot] = ((e & 0xFFFFu) << 8) | (((e >> 16) & 0x7Fu) << 25);
    }
}

// One wave per dst: gather h_bf[src] (256B, 1 dword/lane), accumulate 4 basis
// float2 pairs/lane (v_pk_fma_f32), scale by norm, store bf16 A-panel row.
__global__ __launch_bounds__(256) void aggregate_pre(
    const unsigned short* __restrict__ hbf,
    const int* __restrict__ rowptr,
    const unsigned int* __restrict__ sedge,
    const float* __restrict__ coeff,
    const float* __restrict__ norm,
    unsigned short* __restrict__ A2, int N, int R)
{
    __shared__ float scoef[512];               // R*4 <= 512
    for (int i = threadIdx.x; i < R * 4; i += 256) scoef[i] = coeff[i];
    __syncthreads();

    const int wave = threadIdx.x >> 6;
    const int lane = threadIdx.x & 63;
    const int d = blockIdx.x * 4 + wave;
    if (d >= N) return;
    int i = rowptr[d];
    const int end = rowptr[d + 1];

    const char* hbase = (const char*)hbf + lane * 4;

    floatx2 a0 = {0.f, 0.f}, a1 = {0.f, 0.f}, a2 = {0.f, 0.f}, a3 = {0.f, 0.f};

#define EDGE_LOAD(v, u) \
    unsigned int u = *(const unsigned int*)(hbase + ((v) & 0x00FFFF00u));
#define EDGE_MATH(v, u) { \
    const float4 c = *(const float4*)((const char*)scoef + (((v) >> 25) << 4)); \
    floatx2 hp; \
    hp[0] = __uint_as_float((u) << 16); \
    hp[1] = __uint_as_float((u) & 0xFFFF0000u); \
    a0 = __builtin_elementwise_fma((floatx2){c.x, c.x}, hp, a0); \
    a1 = __builtin_elementwise_fma((floatx2){c.y, c.y}, hp, a1); \
    a2 = __builtin_elementwise_fma((floatx2){c.z, c.z}, hp, a2); \
    a3 = __builtin_elementwise_fma((floatx2){c.w, c.w}, hp, a3); }

    while (i < end && (i & 3)) {
        unsigned int v = sedge[i];
        EDGE_LOAD(v, u)
        EDGE_MATH(v, u)
        ++i;
    }
    for (; i + 8 <= end; i += 8) {
        uint4 e0 = *(const uint4*)(sedge + i);
        uint4 e1 = *(const uint4*)(sedge + i + 4);
        EDGE_LOAD(e0.x, u0) EDGE_LOAD(e0.y, u1) EDGE_LOAD(e0.z, u2) EDGE_LOAD(e0.w, u3)
        EDGE_LOAD(e1.x, u4) EDGE_LOAD(e1.y, u5) EDGE_LOAD(e1.z, u6) EDGE_LOAD(e1.w, u7)
        EDGE_MATH(e0.x, u0) EDGE_MATH(e0.y, u1) EDGE_MATH(e0.z, u2) EDGE_MATH(e0.w, u3)
        EDGE_MATH(e1.x, u4) EDGE_MATH(e1.y, u5) EDGE_MATH(e1.z, u6) EDGE_MATH(e1.w, u7)
    }
    for (; i + 4 <= end; i += 4) {
        uint4 e0 = *(const uint4*)(sedge + i);
        EDGE_LOAD(e0.x, u0) EDGE_LOAD(e0.y, u1) EDGE_LOAD(e0.z, u2) EDGE_LOAD(e0.w, u3)
        EDGE_MATH(e0.x, u0) EDGE_MATH(e0.y, u1) EDGE_MATH(e0.z, u2) EDGE_MATH(e0.w, u3)
    }
    for (; i < end; ++i) {
        unsigned int v = sedge[i];
        EDGE_LOAD(v, u)
        EDGE_MATH(v, u)
    }
#undef EDGE_LOAD
#undef EDGE_MATH

    const float nm = norm[d];
    unsigned short* row = A2 + (size_t)d * 512 + lane * 2;
    *(unsigned int*)(row)       = (unsigned int)f2bf(a0[0] * nm) | ((unsigned int)f2bf(a0[1] * nm) << 16);
    *(unsigned int*)(row + 128) = (unsigned int)f2bf(a1[0] * nm) | ((unsigned int)f2bf(a1[1] * nm) << 16);
    *(unsigned int*)(row + 256) = (unsigned int)f2bf(a2[0] * nm) | ((unsigned int)f2bf(a2[1] * nm) << 16);
    *(unsigned int*)(row + 384) = (unsigned int)f2bf(a3[0] * nm) | ((unsigned int)f2bf(a3[1] * nm) << 16);
}

// out = relu([A2 | h_bf] @ WT2^T): (N,640)@(640,128), LDS-tiled MFMA GEMM.
__global__ __launch_bounds__(256) void final_gemm(
    const unsigned short* __restrict__ A2,    // (N,512) bf16
    const unsigned short* __restrict__ hbf,   // (N,128) bf16
    const unsigned short* __restrict__ WT2,   // (128,640) bf16 [col][k]
    float* __restrict__ out, int N)
{
    __shared__ char sA[16384];   // [kc 0..7][row 0..127] x 16B
    __shared__ char sB[16384];   // [kc 0..7][col 0..127] x 16B
    const int t = threadIdx.x;
    const int w = t >> 6;
    const int lane = t & 63;
    const int quad = lane >> 4;
    const int low  = lane & 15;
    const int wr = w >> 1, wc = w & 1;   // 2x2 wave grid of 64x64 sub-tiles
    const int m0 = blockIdx.x * 128;

    floatx4 acc[4][4];
#pragma unroll
    for (int mt = 0; mt < 4; ++mt)
#pragma unroll
        for (int nt = 0; nt < 4; ++nt) acc[mt][nt] = (floatx4){0.f, 0.f, 0.f, 0.f};

    for (int it = 0; it < 10; ++it) {
        const int k0 = it * 64;
#pragma unroll
        for (int i = 0; i < 4; ++i) {
            const int slot = i * 256 + t;          // 0..1023
            const int kc  = slot >> 7;             // 0..7
            const int idx = slot & 127;            // row / col
            int grow = m0 + idx;
            if (grow >= N) grow = N - 1;           // clamp loads; stores guarded
            const unsigned short* gA = (k0 < 512)
                ? A2  + (size_t)grow * 512 + k0 + kc * 8
                : hbf + (size_t)grow * 128 + (k0 - 512) + kc * 8;
            const unsigned short* gB = WT2 + (size_t)idx * 640 + k0 + kc * 8;
            stage16(gA, sA + (size_t)(i * 256 + w * 64) * 16, lane);
            stage16(gB, sB + (size_t)(i * 256 + w * 64) * 16, lane);
        }
        __syncthreads();

#pragma unroll
        for (int ks = 0; ks < 2; ++ks) {
            bf16x8 af[4], bfr[4];
#pragma unroll
            for (int mt = 0; mt < 4; ++mt)
                af[mt] = *(const bf16x8*)(sA + (size_t)(((ks * 4 + quad) << 7) + wr * 64 + mt * 16 + low) * 16);
#pragma unroll
            for (int nt = 0; nt < 4; ++nt)
                bfr[nt] = *(const bf16x8*)(sB + (size_t)(((ks * 4 + quad) << 7) + wc * 64 + nt * 16 + low) * 16);
#pragma unroll
            for (int mt = 0; mt < 4; ++mt)
#pragma unroll
                for (int nt = 0; nt < 4; ++nt)
                    acc[mt][nt] = __builtin_amdgcn_mfma_f32_16x16x32_bf16(af[mt], bfr[nt], acc[mt][nt], 0, 0, 0);
        }
        __syncthreads();
    }

    // C/D: col=lane&15, row=(lane>>4)*4+reg
#pragma unroll
    for (int mt = 0; mt < 4; ++mt) {
#pragma unroll
        for (int nt = 0; nt < 4; ++nt) {
            const int c = wc * 64 + nt * 16 + low;
#pragma unroll
            for (int r = 0; r < 4; ++r) {
                int rr = m0 + wr * 64 + mt * 16 + quad * 4 + r;
                if (rr < N) out[(size_t)rr * 128 + c] = fmaxf(acc[mt][nt][r], 0.f);
            }
        }
    }
}

extern "C" void kernel_launch(void* const* d_in, const int* in_sizes, int n_in,
                              void* d_out, int out_size, void* d_ws, size_t ws_size,
                              hipStream_t stream)
{
    const float* h     = (const float*)d_in[0];
    const float* norm  = (const float*)d_in[1];
    const int*   src   = (const int*)d_in[2];
    const int*   dst   = (const int*)d_in[3];
    const int*   rel   = (const int*)d_in[4];
    const float* basis = (const float*)d_in[5];
    const float* coeff = (const float*)d_in[6];
    const float* loopw = (const float*)d_in[7];
    float* out = (float*)d_out;

    const int N = in_sizes[1];       // 50000
    const int E = in_sizes[2];       // 800000
    const int R = in_sizes[6] / 4;   // 100

    const int nB      = (N + 255) >> 8;          // 196 coarse buckets
    const int nblkH   = (E + EPB - 1) / EPB;     // 196 edge chunks
    const int M       = nB * nblkH;
    const int nb_conv = (N * 64 + 255) / 256;    // 12500

    char* ws = (char*)d_ws;
    size_t off = 0;
    auto walloc = [&](size_t bytes) -> char* {
        char* p = ws + off;
        off = (off + bytes + 255) & ~(size_t)255;
        return p;
    };
    unsigned short* A2       = (unsigned short*)walloc((size_t)N * 512 * 2);  // 51.2 MB
    unsigned short* hbf      = (unsigned short*)walloc((size_t)N * 128 * 2);  // 12.8 MB
    unsigned short* WT2      = (unsigned short*)walloc(128 * 640 * 2);
    int*            gh       = (int*)walloc((size_t)M * 4);
    int*            binStart = (int*)walloc((size_t)(nB + 1) * 4);
    unsigned int*   tmp      = (unsigned int*)walloc((size_t)E * 4);
    unsigned int*   sedge    = (unsigned int*)walloc((size_t)E * 4);
    int*            rowptr   = (int*)walloc((size_t)(N + 1) * 4);

    prep_all<<<nb_conv + nblkH + 128, 256, 0, stream>>>(
        h, hbf, N * 64, dst, gh, E, nB, nblkH, basis, loopw, WT2, nb_conv);
    scatter_bkt<<<nblkH, 256, 0, stream>>>(dst, src, rel, gh, binStart, tmp, E, nB, nblkH);
    bucket_sort<<<nB, 256, 0, stream>>>(tmp, binStart, sedge, rowptr, E, N, nB);
    aggregate_pre<<<(N + 3) / 4, 256, 0, stream>>>(hbf, rowptr, sedge, coeff, norm, A2, N, R);
    final_gemm<<<(N + 127) / 128, 256, 0, stream>>>(A2, hbf, WT2, out, N);
}